// Round 8
// baseline (48.607 us; speedup 1.0000x reference)
//
#include <hip/hip_runtime.h>

typedef unsigned int u32;
typedef unsigned short u16;
typedef __bf16 bf16x8 __attribute__((ext_vector_type(8)));
typedef float f32x4 __attribute__((ext_vector_type(4)));

static __device__ __forceinline__ u16 f2bf(float f) {
  u32 u = __float_as_uint(f);
  return (u16)((u + 0x7fffu + ((u >> 16) & 1u)) >> 16);  // RTNE
}
static __device__ __forceinline__ float b2f(u16 v) {
  return __uint_as_float(((u32)v) << 16);
}
static __device__ __forceinline__ u32 pk2(u16 lo, u16 hi) {
  return (u32)lo | ((u32)hi << 16);
}

// ---- prep: zero out; L2-normalize shapelets over s; emit bf16 in FRAGMENT order ----
// chunk = c*8 + kt*2 + ks (512 u16); lane L=(m+16h) holds elems [L*8,L*8+8)
// = shn[k=kt*16+m][s=ks*32+8h .. +7].
__global__ __launch_bounds__(256) void prep_kernel(const float* __restrict__ sh,
                                                   u16* __restrict__ shn2,
                                                   float* __restrict__ out) {
  if (blockIdx.x == 0) {  // zero the 32*64 output (atomicMax target)
    float4 z = {0.f, 0.f, 0.f, 0.f};
    *(float4*)&out[threadIdx.x * 8] = z;
    *(float4*)&out[threadIdx.x * 8 + 4] = z;
  }
  const int s = threadIdx.x & 63;
  const int wv = threadIdx.x >> 6;
  const int row0 = blockIdx.x * 16 + wv * 4;
#pragma unroll
  for (int r = 0; r < 4; ++r) {
    const int row = row0 + r;  // = c*64 + k
    float v = sh[row * 64 + s];
    float ss = v * v;
#pragma unroll
    for (int o = 1; o < 64; o <<= 1) ss += __shfl_xor(ss, o, 64);
    float iw = 1.0f / fmaxf(sqrtf(ss), 1e-8f);
    const int c = row >> 6, k = row & 63;
    const int chunk = c * 8 + (k >> 4) * 2 + (s >> 5);
    const int pos = ((k & 15) + (((s & 31) >> 3) << 4)) * 8 + (s & 7);
    shn2[chunk * 512 + pos] = f2bf(v * iw);
  }
}

#define WT 128
#define CSTRIDE 104   // u32 per (copy, channel): 96 data + 8 pad (≡8 mod 32)
#define PSTRIDE 1680  // u32 per parity copy: 16*104 + 16 (≡16 mod 32)
#define IWS 136       // u16 stride of invwb rows (128 + 8 pad)

// grid (32, 32): blockIdx.x = w-tile (128 w's), blockIdx.y = b.
// 8 waves = 4 w-groups x 2 k-groups; wave tile = 32 w x 32 k.
// Roles: M = w (A = windows, LDS b32 reads), N = k (B = shapelets, global coalesced).
__global__ __launch_bounds__(512, 6) void main_kernel(const float* __restrict__ x,
                                                      const u16* __restrict__ shn2,
                                                      float* __restrict__ out) {
  __shared__ u32 xs[2 * PSTRIDE];  // 13440 B: bf16 x-slice, 2 parity pair-packed copies
  __shared__ u16 invwb[16 * IWS];  // 4352 B : bf16 inv-window-norms (pre-multiplied 1/C)
  __shared__ int redbuf[64];       // per-block max reduction

  const int tid = threadIdx.x;
  const int lane = tid & 63;
  const int wid = tid >> 6;
  const int w0 = blockIdx.x * WT;
  const int b = blockIdx.y;
  const float* xb = x + (size_t)b * 16 * 4096;

  if (tid < 64) redbuf[tid] = 0;

  // ---- phase A1: stage x-slice as bf16, 2 parity copies.  copy p at pair j
  //      holds elems (2j+p, 2j+p+1).  thread (c=tid>>5, q=tid&31), q<24:
  //      owns elems [8q, 8q+8), loads 12 for the shifted copy. ----
  {
    const int c = tid >> 5;
    const int q = tid & 31;
    if (q < 24) {
      const float* xc = xb + c * 4096;
      const int e0 = w0 + 8 * q;
      float xv[12];
      if (e0 + 11 < 4096) {
#pragma unroll
        for (int r = 0; r < 3; ++r) *(float4*)&xv[4 * r] = *(const float4*)&xc[e0 + 4 * r];
      } else {
#pragma unroll
        for (int j = 0; j < 12; ++j) {
          int g = e0 + j;
          xv[j] = xc[g < 4096 ? g : 4095];
        }
      }
      u16 bf[10];
#pragma unroll
      for (int j = 0; j < 10; ++j) bf[j] = f2bf(xv[j]);
      u32* d0 = &xs[c * CSTRIDE + 4 * q];
      *(uint4*)d0 = make_uint4(pk2(bf[0], bf[1]), pk2(bf[2], bf[3]),
                               pk2(bf[4], bf[5]), pk2(bf[6], bf[7]));
      u32* d1 = d0 + PSTRIDE;
      *(uint4*)d1 = make_uint4(pk2(bf[1], bf[2]), pk2(bf[3], bf[4]),
                               pk2(bf[5], bf[6]), pk2(bf[7], bf[8]));
    }
  }

  // ---- phase A2: window inverse norms, streaming; 4 windows per thread ----
  {
    const int c = tid >> 5;
    const int wb = (tid & 31) * 4;
    const float* xc = xb + c * 4096;
    const int e0 = w0 + wb;
    float hd[4], tl[4], ss = 0.f;
    if (e0 + 67 < 4096) {
#pragma unroll
      for (int r = 0; r < 16; ++r) {
        float4 v = *(const float4*)&xc[e0 + 4 * r];
        if (r < 1) { hd[0] = v.x; hd[1] = v.y; hd[2] = v.z; hd[3] = v.w; }
        ss += v.x * v.x + v.y * v.y + v.z * v.z + v.w * v.w;
      }
      float4 v = *(const float4*)&xc[e0 + 64];
      tl[0] = v.x; tl[1] = v.y; tl[2] = v.z; tl[3] = v.w;
    } else {
#pragma unroll
      for (int j = 0; j < 68; ++j) {  // fully unrolled -> compile-time indices
        int g = e0 + j;
        float v = xc[g < 4096 ? g : 4095];
        if (j < 4) hd[j] = v;
        if (j >= 64) tl[j - 64] = v;
        if (j < 64) ss += v * v;
      }
    }
    u16 ov[4];
#pragma unroll
    for (int i = 0; i < 4; ++i) {
      float iw = 0.0625f / fmaxf(sqrtf(fmaxf(ss, 0.f)), 1e-8f);
      ov[i] = (e0 + i < 4033) ? f2bf(iw) : (u16)0;  // kill padded windows
      ss += tl[i] * tl[i] - hd[i] * hd[i];
    }
    *(uint2*)&invwb[c * IWS + wb] = make_uint2(pk2(ov[0], ov[1]), pk2(ov[2], ov[3]));
  }

  __syncthreads();  // the ONLY barrier before the epilogue

  // ---- phase B: 16 channels, barrier-free ----
  f32x4 acc[2][2];  // [mt][nt], 16 regs
#pragma unroll
  for (int mt = 0; mt < 2; ++mt)
#pragma unroll
    for (int nt = 0; nt < 2; ++nt) acc[mt][nt] = (f32x4){0.f, 0.f, 0.f, 0.f};

  const int m = lane & 15;
  const int h = lane >> 4;
  const int wgrp = wid >> 1;  // 0..3: 32 windows each
  const int kgrp = wid & 1;   // 0..1: 32 k each
  // pair index: elems q0 = 32*wgrp + m + 8h + 16*f  ->  pair (q0>>1), parity m&1
  const u32* xbase = xs + (m & 1) * PSTRIDE;
  const int jp = 16 * wgrp + (m >> 1) + 4 * h;  // + 8*f, + c*CSTRIDE
  const u16* shb = shn2 + lane * 8 + kgrp * 2 * 1024;  // + c*4096 + (nt*2+ks)*512
  const int iwoff = 32 * wgrp + 4 * h;                 // + c*IWS + 16*mt

#pragma unroll 2
  for (int c = 0; c < 16; ++c) {
    const u32* xc = xbase + c * CSTRIDE;
    bf16x8 af[4];  // f = mt + 2*ks  (g-sharing)
#pragma unroll
    for (int f = 0; f < 4; ++f) {
      const u32* p = xc + jp + 8 * f;
      af[f] = __builtin_bit_cast(bf16x8, make_uint4(p[0], p[1], p[2], p[3]));
    }
    f32x4 iwq[2];
#pragma unroll
    for (int mt = 0; mt < 2; ++mt) {
      ushort4 r4 = *(const ushort4*)&invwb[c * IWS + iwoff + 16 * mt];
      iwq[mt] = (f32x4){b2f(r4.x), b2f(r4.y), b2f(r4.z), b2f(r4.w)};
    }
    const u16* sc = shb + c * 4096;
#pragma unroll
    for (int nt = 0; nt < 2; ++nt) {  // b live range = 8 regs
      bf16x8 b0 = __builtin_bit_cast(bf16x8, *(const uint4*)(sc + (nt * 2 + 0) * 512));
      bf16x8 b1 = __builtin_bit_cast(bf16x8, *(const uint4*)(sc + (nt * 2 + 1) * 512));
#pragma unroll
      for (int mt = 0; mt < 2; ++mt) {
        f32x4 d = {0.f, 0.f, 0.f, 0.f};
        d = __builtin_amdgcn_mfma_f32_16x16x32_bf16(af[mt],     b0, d, 0, 0, 0);
        d = __builtin_amdgcn_mfma_f32_16x16x32_bf16(af[mt + 2], b1, d, 0, 0, 0);
        acc[mt][nt] += iwq[mt] * d;
      }
    }
  }

  // ---- epilogue: relu+max over w (rows), shfl over h, redbuf, 1 atomic/out ----
#pragma unroll
  for (int nt = 0; nt < 2; ++nt) {
    float v = 0.f;  // relu floor
#pragma unroll
    for (int mt = 0; mt < 2; ++mt)
      v = fmaxf(v, fmaxf(fmaxf(acc[mt][nt].x, acc[mt][nt].y),
                         fmaxf(acc[mt][nt].z, acc[mt][nt].w)));
    v = fmaxf(v, __shfl_xor(v, 16, 64));
    v = fmaxf(v, __shfl_xor(v, 32, 64));
    if (lane < 16) atomicMax(&redbuf[kgrp * 32 + nt * 16 + lane], __float_as_int(v));
  }
  __syncthreads();
  if (tid < 64) atomicMax((int*)&out[b * 64 + tid], redbuf[tid]);
}

extern "C" void kernel_launch(void* const* d_in, const int* in_sizes, int n_in,
                              void* d_out, int out_size, void* d_ws, size_t ws_size,
                              hipStream_t stream) {
  const float* x = (const float*)d_in[0];
  const float* sh = (const float*)d_in[1];
  float* out = (float*)d_out;
  u16* shn2 = (u16*)d_ws;  // 16*64*64 bf16 = 131072 B, fragment-ordered

  prep_kernel<<<dim3(64), dim3(256), 0, stream>>>(sh, shn2, out);
  main_kernel<<<dim3(32, 32), dim3(512), 0, stream>>>(x, shn2, out);
}